// Round 1
// baseline (401.300 us; speedup 1.0000x reference)
//
#include <hip/hip_runtime.h>

// ---------------------------------------------------------------------------
// TraceSemanticHandshakeV342: fused concat+LayerNorm+Linear+GELU+Linear+GELU
// b=4, m=256, h=64, d=256, CAT=1283.  Rows = b*m*h = 65536.
// Strategy: one block per (b,m): M=64 rows (h), N=256, K=1280 bf16 MFMA GEMM
// with LN folded into the epilogue (rs/mu fixup + Sg/Sb column sums), tail-3
// features in f32.  Weights pre-transposed+gamma-folded to bf16 in d_ws.
// ---------------------------------------------------------------------------

typedef float  f32x4 __attribute__((ext_vector_type(4)));
typedef short  s16x8 __attribute__((ext_vector_type(8)));

__device__ __forceinline__ unsigned short f2bf(float f) {
    unsigned u = __builtin_bit_cast(unsigned, f);
    return (unsigned short)((u + 0x7fffu + ((u >> 16) & 1u)) >> 16);
}
__device__ __forceinline__ unsigned f2bf_pk(float lo, float hi) {
    unsigned ulo = __builtin_bit_cast(unsigned, lo);
    unsigned uhi = __builtin_bit_cast(unsigned, hi);
    ulo = (ulo + 0x7fffu + ((ulo >> 16) & 1u)) >> 16;
    uhi = (uhi + 0x7fffu + ((uhi >> 16) & 1u)) & 0xffff0000u;
    return ulo | uhi;
}
// tanh-form GELU: x*sigmoid(2*0.79788456*(x+0.044715 x^3)); max err ~4e-4.
__device__ __forceinline__ float gelu_t(float x) {
    float u2 = 1.5957691216057308f * x + 0.07135481627f * (x * x * x);
    float e  = __expf(u2);
    float r  = __builtin_amdgcn_rcpf(e + 1.0f);   // 1/(1+e^{2u}) ; e=inf -> 0
    return x - x * r;                              // x*sigmoid(2u)
}

// ---------------------------------------------------------------------------
// Prep kernel: builds in d_ws
//   Sg[256], Sb[256] f32 (atomics, ws pre-zeroed by memset)
//   W1T bf16 [256][1280]: W1T[n][k] = gamma[k]*W1[k][n]   (k<1280)
//   W2T bf16 [256][256] : W2T[n][k] = W2[k][n]
// blocks 0..319: W1 transpose tiles; 320..383: W2; 384..423: Sg/Sb sums
// ---------------------------------------------------------------------------
__global__ void __launch_bounds__(256)
prep_k(const float* __restrict__ W1, const float* __restrict__ W2,
       const float* __restrict__ gamma, const float* __restrict__ beta,
       float* __restrict__ Sg, float* __restrict__ Sb,
       short* __restrict__ w1t, short* __restrict__ w2t)
{
    __shared__ float tile[32][33];
    const int blk = blockIdx.x;
    const int tx = threadIdx.x & 31, ty = threadIdx.x >> 5;
    if (blk < 320) {
        const int kt = blk >> 3, nt = blk & 7;
#pragma unroll
        for (int j = 0; j < 4; ++j) {
            int kl = ty + 8 * j;
            int k  = kt * 32 + kl;
            tile[kl][tx] = gamma[k] * W1[k * 256 + nt * 32 + tx];
        }
        __syncthreads();
#pragma unroll
        for (int j = 0; j < 4; ++j) {
            int nl = ty + 8 * j;
            int n  = nt * 32 + nl;
            w1t[n * 1280 + kt * 32 + tx] = (short)f2bf(tile[tx][nl]);
        }
    } else if (blk < 384) {
        const int b2 = blk - 320;
        const int kt = b2 >> 3, nt = b2 & 7;
#pragma unroll
        for (int j = 0; j < 4; ++j) {
            int kl = ty + 8 * j;
            int k  = kt * 32 + kl;
            tile[kl][tx] = W2[k * 256 + nt * 32 + tx];
        }
        __syncthreads();
#pragma unroll
        for (int j = 0; j < 4; ++j) {
            int nl = ty + 8 * j;
            int n  = nt * 32 + nl;
            w2t[n * 256 + kt * 32 + tx] = (short)f2bf(tile[tx][nl]);
        }
    } else {
        const int kb = (blk - 384) * 32;
        const int n  = threadIdx.x;
        float sg = 0.f, sb = 0.f;
#pragma unroll
        for (int j = 0; j < 32; ++j) {
            int k = kb + j;
            float w = W1[k * 256 + n];
            sg += gamma[k] * w;
            sb += beta[k]  * w;
        }
        atomicAdd(&Sg[n], sg);
        atomicAdd(&Sb[n], sb);
    }
}

// ---------------------------------------------------------------------------
// Main fused kernel. grid = 1024 (one per (b,m)); block = 256 (4 waves).
// Wave w owns columns n in [w*64, w*64+64); all 4 M-tiles (16x16x32 MFMA).
// LDS A buffer: 64 rows x 256 bf16, 16B-chunk XOR swizzle (chunk ^= row&7).
// ---------------------------------------------------------------------------
__global__ void __launch_bounds__(256)
fused_main(const float* __restrict__ token, const float* __restrict__ step,
           const float* __restrict__ dyn,   const float* __restrict__ sem,
           const float* __restrict__ trace, const float* __restrict__ rel,
           const float* __restrict__ vis,   const float* __restrict__ gamma,
           const float* __restrict__ beta,  const float* __restrict__ W1,
           const float* __restrict__ b1v,   const float* __restrict__ b2v,
           const float* __restrict__ Sg,    const float* __restrict__ Sb,
           const short* __restrict__ w1t,   const short* __restrict__ w2t,
           float* __restrict__ out)
{
    __shared__ uint4 As[64 * 32];                 // 32 KB: A tile / y1 tile
    __shared__ float rsum1[64], rsum2[64];
    __shared__ float mu_s[64], rs_s[64], t0s[64], t1s[64], t2s[64];

    const int t    = threadIdx.x;
    const int bm   = blockIdx.x;          // b*256 + m
    const int b_i  = bm >> 8;
    const int lane = t & 63;
    const int wv   = t >> 6;
    const int l15  = lane & 15;
    const int q    = lane >> 4;
    const int n0   = wv * 64;

    // staging role: 4 threads per row, 64 f32 each
    const int sr = t >> 2;
    const int sq = t & 3;

    const float* srcs[5];
    srcs[0] = token + bm * 256 + sq * 64;                       // broadcast row
    srcs[1] = step  + (b_i * 64 + sr) * 256 + sq * 64;
    srcs[2] = dyn   + (bm * 64 + sr) * 256 + sq * 64;
    srcs[3] = sem   + (bm * 64 + sr) * 256 + sq * 64;
    srcs[4] = trace + (bm * 64 + sr) * 256 + sq * 64;

    f32x4 acc[4][4];
#pragma unroll
    for (int i = 0; i < 4; ++i)
#pragma unroll
        for (int j = 0; j < 4; ++j)
            acc[i][j] = (f32x4){0.f, 0.f, 0.f, 0.f};

    float s1 = 0.f, s2 = 0.f;

#pragma unroll
    for (int seg = 0; seg < 5; ++seg) {
        __syncthreads();
        const float4* s4 = (const float4*)srcs[seg];
#pragma unroll
        for (int i = 0; i < 8; ++i) {
            float4 a = s4[2 * i];
            float4 b = s4[2 * i + 1];
            s1 += a.x + a.y + a.z + a.w + b.x + b.y + b.z + b.w;
            s2 += a.x * a.x + a.y * a.y + a.z * a.z + a.w * a.w
                + b.x * b.x + b.y * b.y + b.z * b.z + b.w * b.w;
            uint4 p;
            p.x = f2bf_pk(a.x, a.y);
            p.y = f2bf_pk(a.z, a.w);
            p.z = f2bf_pk(b.x, b.y);
            p.w = f2bf_pk(b.z, b.w);
            int kc8 = sq * 8 + i;                         // 16B chunk 0..31
            As[sr * 32 + (kc8 ^ (sr & 7))] = p;
        }
        __syncthreads();
        const short* wseg = w1t + seg * 256;
#pragma unroll
        for (int kc = 0; kc < 8; ++kc) {
            s16x8 bfr[4];
#pragma unroll
            for (int nt = 0; nt < 4; ++nt) {
                int n = n0 + nt * 16 + l15;
                bfr[nt] = *(const s16x8*)(wseg + n * 1280 + kc * 32 + q * 8);
            }
            s16x8 afr[4];
#pragma unroll
            for (int mt = 0; mt < 4; ++mt) {
                int m = mt * 16 + l15;
                int chunk = (kc * 4 + q) ^ (m & 7);
                afr[mt] = *(const s16x8*)&As[m * 32 + chunk];
            }
#pragma unroll
            for (int mt = 0; mt < 4; ++mt)
#pragma unroll
                for (int nt = 0; nt < 4; ++nt)
                    acc[mt][nt] = __builtin_amdgcn_mfma_f32_16x16x32_bf16(
                        afr[mt], bfr[nt], acc[mt][nt], 0, 0, 0);
        }
    }

    // ---- per-row stats (Sum x, Sum x^2 over 1283) -------------------------
    s1 += __shfl_xor(s1, 1); s1 += __shfl_xor(s1, 2);
    s2 += __shfl_xor(s2, 1); s2 += __shfl_xor(s2, 2);
    if (sq == 0) { rsum1[sr] = s1; rsum2[sr] = s2; }
    __syncthreads();
    if (t < 64) {
        int r = t;
        float x0 = rel[(bm * 64 + r) * 2 + 0];
        float x1 = rel[(bm * 64 + r) * 2 + 1];
        float x2 = vis[bm * 64 + r];
        float S1 = rsum1[r] + x0 + x1 + x2;
        float S2 = rsum2[r] + x0 * x0 + x1 * x1 + x2 * x2;
        const float inv = 1.0f / 1283.0f;
        float mu  = S1 * inv;
        float var = S2 * inv - mu * mu;
        float rs  = rsqrtf(var + 1e-5f);
        mu_s[r] = mu;
        rs_s[r] = rs;
        t0s[r] = (x0 - mu) * rs * gamma[1280] + beta[1280];
        t1s[r] = (x1 - mu) * rs * gamma[1281] + beta[1281];
        t2s[r] = (x2 - mu) * rs * gamma[1282] + beta[1282];
    }
    __syncthreads();

    // ---- epilogue 1: LN fixup + tail + bias + GELU -> y1 bf16 into As -----
    unsigned short* y16 = (unsigned short*)As;
#pragma unroll
    for (int nt = 0; nt < 4; ++nt) {
        int n = n0 + nt * 16 + l15;
        float sg  = Sg[n], sb = Sb[n], bb = b1v[n];
        float wt0 = W1[1280 * 256 + n];
        float wt1 = W1[1281 * 256 + n];
        float wt2 = W1[1282 * 256 + n];
#pragma unroll
        for (int mt = 0; mt < 4; ++mt) {
#pragma unroll
            for (int r4 = 0; r4 < 4; ++r4) {
                int r = mt * 16 + q * 4 + r4;
                float rsv = rs_s[r], muv = mu_s[r];
                float v = rsv * acc[mt][nt][r4] - rsv * muv * sg + sb + bb
                        + t0s[r] * wt0 + t1s[r] * wt1 + t2s[r] * wt2;
                v = gelu_t(v);
                int chunk = (n >> 3) ^ (r & 7);
                y16[(r * 32 + chunk) * 8 + (n & 7)] = f2bf(v);
            }
        }
    }
    __syncthreads();

    // ---- GEMM2: y1 (64x256 bf16 in LDS) @ W2T (global bf16) ---------------
    f32x4 acc2[4][4];
#pragma unroll
    for (int i = 0; i < 4; ++i)
#pragma unroll
        for (int j = 0; j < 4; ++j)
            acc2[i][j] = (f32x4){0.f, 0.f, 0.f, 0.f};

#pragma unroll
    for (int kc = 0; kc < 8; ++kc) {
        s16x8 bfr[4];
#pragma unroll
        for (int nt = 0; nt < 4; ++nt) {
            int n = n0 + nt * 16 + l15;
            bfr[nt] = *(const s16x8*)(w2t + n * 256 + kc * 32 + q * 8);
        }
        s16x8 afr[4];
#pragma unroll
        for (int mt = 0; mt < 4; ++mt) {
            int m = mt * 16 + l15;
            int chunk = (kc * 4 + q) ^ (m & 7);
            afr[mt] = *(const s16x8*)&As[m * 32 + chunk];
        }
#pragma unroll
        for (int mt = 0; mt < 4; ++mt)
#pragma unroll
            for (int nt = 0; nt < 4; ++nt)
                acc2[mt][nt] = __builtin_amdgcn_mfma_f32_16x16x32_bf16(
                    afr[mt], bfr[nt], acc2[mt][nt], 0, 0, 0);
    }

    // ---- epilogue 2: + b2, GELU, store f32 --------------------------------
#pragma unroll
    for (int nt = 0; nt < 4; ++nt) {
        int n = n0 + nt * 16 + l15;
        float bb = b2v[n];
#pragma unroll
        for (int mt = 0; mt < 4; ++mt)
#pragma unroll
            for (int r4 = 0; r4 < 4; ++r4) {
                int r = mt * 16 + q * 4 + r4;
                out[(bm * 64 + r) * 256 + n] = gelu_t(acc2[mt][nt][r4] + bb);
            }
    }
}

// ---------------------------------------------------------------------------
extern "C" void kernel_launch(void* const* d_in, const int* in_sizes, int n_in,
                              void* d_out, int out_size, void* d_ws, size_t ws_size,
                              hipStream_t stream) {
    const float* token = (const float*)d_in[0];
    const float* step  = (const float*)d_in[1];
    const float* dyn   = (const float*)d_in[2];
    const float* sem   = (const float*)d_in[3];
    const float* trace = (const float*)d_in[4];
    const float* rel   = (const float*)d_in[5];
    const float* vis   = (const float*)d_in[6];
    const float* gamma = (const float*)d_in[7];
    const float* beta  = (const float*)d_in[8];
    const float* W1    = (const float*)d_in[9];
    const float* b1    = (const float*)d_in[10];
    const float* W2    = (const float*)d_in[11];
    const float* b2    = (const float*)d_in[12];

    // ws layout: [0,1KB) Sg f32, [1KB,2KB) Sb f32, then W1T bf16 (655360 B),
    // then W2T bf16 (131072 B).  Total 788480 B.
    float* Sg  = (float*)d_ws;
    float* Sb  = Sg + 256;
    short* w1t = (short*)((char*)d_ws + 2048);
    short* w2t = w1t + 1280 * 256;
    float* out = (float*)d_out;

    hipMemsetAsync(d_ws, 0, 2048, stream);
    hipLaunchKernelGGL(prep_k, dim3(424), dim3(256), 0, stream,
                       W1, W2, gamma, beta, Sg, Sb, w1t, w2t);
    hipLaunchKernelGGL(fused_main, dim3(1024), dim3(256), 0, stream,
                       token, step, dyn, sem, trace, rel, vis, gamma, beta,
                       W1, b1, b2, Sg, Sb, w1t, w2t, out);
}